// Round 9
// baseline (285.323 us; speedup 1.0000x reference)
//
#include <hip/hip_runtime.h>
#include <hip/hip_bf16.h>

typedef float f32x4 __attribute__((ext_vector_type(4)));
typedef short bf16x8 __attribute__((ext_vector_type(8)));

__device__ __forceinline__ float4 ld4(const float* p){ return *reinterpret_cast<const float4*>(p); }
__device__ __forceinline__ unsigned short f2bf(float f){
  unsigned int u = __float_as_uint(f);
  u = (u + 0x7fffu + ((u>>16)&1u)) >> 16;
  return (unsigned short)u;
}
__device__ __forceinline__ float bflo(unsigned int u){ return __uint_as_float(u<<16); }
__device__ __forceinline__ float bfhi(unsigned int u){ return __uint_as_float(u & 0xffff0000u); }
__device__ __forceinline__ float bfs(short s){ return __uint_as_float(((unsigned)(unsigned short)s)<<16); }
__device__ __forceinline__ float ftanh(float x){
  float e = __expf(2.f*x);
  return fmaf(-2.f, __builtin_amdgcn_rcpf(e+1.f), 1.f);
}

// =============== x fp32 -> bf16 ===============
__global__ __launch_bounds__(256) void k_xcast(const float* __restrict__ x, unsigned short* __restrict__ xb, int n8){
  int i = blockIdx.x*256 + threadIdx.x;
  if (i >= n8) return;
  float4 v0 = ld4(&x[(size_t)i*8]);
  float4 v1 = ld4(&x[(size_t)i*8+4]);
  uint4 o;
  o.x = (unsigned)f2bf(v0.x) | ((unsigned)f2bf(v0.y)<<16);
  o.y = (unsigned)f2bf(v0.z) | ((unsigned)f2bf(v0.w)<<16);
  o.z = (unsigned)f2bf(v1.x) | ((unsigned)f2bf(v1.y)<<16);
  o.w = (unsigned)f2bf(v1.z) | ((unsigned)f2bf(v1.w)<<16);
  *reinterpret_cast<uint4*>(&xb[(size_t)i*8]) = o;
}

// =============== CSR build: bucketed ===============
__global__ __launch_bounds__(256) void k_bcount(const int* __restrict__ ei, int* __restrict__ bcnt, int E_, int Et){
  __shared__ int h[64];
  int t = threadIdx.x;
  if (t < 64) h[t] = 0;
  __syncthreads();
  int e0 = blockIdx.x*2048 + t;
  #pragma unroll
  for (int k=0;k<8;k++){
    int e = e0 + k*256;
    if (e < Et){ int d = (e < E_) ? ei[E_ + e] : (e - E_); atomicAdd(&h[d>>10], 1); }
  }
  __syncthreads();
  if (t < 64 && h[t]) atomicAdd(&bcnt[t], h[t]);
}

__global__ __launch_bounds__(64) void k_binit(const int* __restrict__ bcnt, int* __restrict__ bbase,
                                              int* __restrict__ bcursor, int nb){
  int l = threadIdx.x;
  int v = (l < nb) ? bcnt[l] : 0;
  int incl = v;
  #pragma unroll
  for (int d=1; d<64; d<<=1){ int u = __shfl_up(incl, d); if (l>=d) incl += u; }
  int ex = incl - v;
  if (l < nb){ bbase[l] = ex; bcursor[l] = ex; }
  if (l == 63) bbase[nb] = incl;
}

__global__ __launch_bounds__(256) void k_bucket(const int* __restrict__ ei, int* __restrict__ bcursor,
                                                uint2* __restrict__ bdata, int E_, int Et){
  __shared__ int h[64];
  __shared__ int base[64];
  int t = threadIdx.x;
  if (t < 64) h[t] = 0;
  __syncthreads();
  int e0 = blockIdx.x*2048 + t;
  int dv[8], sv[8], rv[8];
  #pragma unroll
  for (int k=0;k<8;k++){
    int e = e0 + k*256;
    if (e < Et){
      int s, d;
      if (e < E_){ s = ei[e]; d = ei[E_+e]; } else { s = e-E_; d = s; }
      dv[k] = d; sv[k] = s;
      rv[k] = atomicAdd(&h[d>>10], 1);
    } else dv[k] = -1;
  }
  __syncthreads();
  if (t < 64 && h[t]) base[t] = atomicAdd(&bcursor[t], h[t]);
  __syncthreads();
  #pragma unroll
  for (int k=0;k<8;k++){
    if (dv[k] >= 0){
      int b = dv[k]>>10;
      bdata[base[b]+rv[k]] = make_uint2((unsigned)dv[k], (unsigned)sv[k]);
    }
  }
}

__global__ __launch_bounds__(512) void k_bhist(const uint2* __restrict__ bdata, const int* __restrict__ bbase,
                                               int* __restrict__ cnt, int N_){
  __shared__ int c[1024];
  int b = blockIdx.x, t = threadIdx.x;
  for (int i=t;i<1024;i+=512) c[i]=0;
  __syncthreads();
  int lo = bbase[b], hi = bbase[b+1];
  for (int i=lo+t; i<hi; i+=512){ unsigned d = bdata[i].x; atomicAdd(&c[d&1023], 1); }
  __syncthreads();
  int n0 = b<<10;
  for (int i=t;i<1024;i+=512){ int n = n0+i; if (n < N_) cnt[n] = c[i]; }
}

__global__ __launch_bounds__(256) void k_scan1(const int* __restrict__ cnt, int* __restrict__ blk, int N_){
  int t = threadIdx.x, b = blockIdx.x;
  int i0 = b*1024 + t*4;
  int s = 0;
  if (i0+3 < N_){ int4 v = *reinterpret_cast<const int4*>(&cnt[i0]); s = v.x+v.y+v.z+v.w; }
  else { for (int j=0;j<4;j++) if (i0+j<N_) s += cnt[i0+j]; }
  #pragma unroll
  for (int d=1; d<64; d<<=1) s += __shfl_xor(s, d);
  __shared__ int ws[4];
  if ((t&63)==0) ws[t>>6] = s;
  __syncthreads();
  if (t==0) blk[b] = ws[0]+ws[1]+ws[2]+ws[3];
}

__global__ __launch_bounds__(64) void k_scan2(const int* __restrict__ blk, int* __restrict__ blkoff,
                                              int* __restrict__ off, int N_, int nblk){
  int l = threadIdx.x;
  int v = (l<nblk)? blk[l] : 0;
  int incl = v;
  #pragma unroll
  for (int d=1; d<64; d<<=1){ int u = __shfl_up(incl, d); if (l>=d) incl += u; }
  if (l<nblk) blkoff[l] = incl - v;
  if (l==63) off[N_] = incl;
}

__global__ __launch_bounds__(256) void k_scan3(const int* __restrict__ cnt, const int* __restrict__ blkoff,
                                               int* __restrict__ off, int N_){
  int t = threadIdx.x, b = blockIdx.x;
  int i0 = b*1024 + t*4;
  int c0=0,c1=0,c2=0,c3=0;
  if (i0+3 < N_){ int4 v = *reinterpret_cast<const int4*>(&cnt[i0]); c0=v.x;c1=v.y;c2=v.z;c3=v.w; }
  else { if(i0<N_)c0=cnt[i0]; if(i0+1<N_)c1=cnt[i0+1]; if(i0+2<N_)c2=cnt[i0+2]; if(i0+3<N_)c3=cnt[i0+3]; }
  int s = c0+c1+c2+c3;
  int incl = s;
  int lane = t&63, w = t>>6;
  #pragma unroll
  for (int d=1; d<64; d<<=1){ int u = __shfl_up(incl, d); if (lane>=d) incl += u; }
  __shared__ int ws[4];
  if (lane==63) ws[w] = incl;
  __syncthreads();
  int wpre = 0;
  #pragma unroll
  for (int k=0;k<4;k++) if (k<w) wpre += ws[k];
  int run = blkoff[b] + wpre + incl - s;
  if (i0  <N_) off[i0]   = run; run += c0;
  if (i0+1<N_) off[i0+1] = run; run += c1;
  if (i0+2<N_) off[i0+2] = run; run += c2;
  if (i0+3<N_) off[i0+3] = run;
}

__global__ __launch_bounds__(512) void k_bscatter(const uint2* __restrict__ bdata, const int* __restrict__ bbase,
                                                  const int* __restrict__ off, int* __restrict__ csr, int N_){
  __shared__ int cur[1024];
  int b = blockIdx.x, t = threadIdx.x;
  int n0 = b<<10;
  for (int i=t;i<1024;i+=512){ int n = n0+i; cur[i] = (n < N_) ? off[n] : 0; }
  __syncthreads();
  int lo = bbase[b], hi = bbase[b+1];
  for (int i=lo+t; i<hi; i+=512){
    uint2 p = bdata[i];
    int pos = atomicAdd(&cur[p.x & 1023], 1);
    csr[pos] = (int)p.y;
  }
}

// =============== weight prep: W fp32 -> Bt bf16 [144 cols][128 k], cols 128..143 = [Ws|Wd] ===============
__global__ __launch_bounds__(256) void k_prep(const float* __restrict__ W0, const float* __restrict__ W12,
    const float* __restrict__ Watt, const float* __restrict__ as0, const float* __restrict__ ad0,
    const float* __restrict__ as12, const float* __restrict__ ad12, unsigned short* __restrict__ dst){
  __shared__ float Wf[64*128];
  int b = blockIdx.x, t = threadIdx.x;
  const float* W = (b==0) ? W0 : (b==3 ? Watt : W12 + (size_t)(b-1)*16384);
  unsigned short* out = dst + (size_t)b*18432;
  const float* as_ = (b==0) ? as0 : as12 + (size_t)(b-1)*128;
  const float* ad_ = (b==0) ? ad0 : ad12 + (size_t)(b-1)*128;

  for (int half=0; half<2; half++){
    #pragma unroll
    for (int p=0;p<8;p++){
      int i = p*256 + t;
      *reinterpret_cast<float4*>(&Wf[i*4]) = ld4(&W[(size_t)half*8192 + i*4]);
    }
    __syncthreads();
    {
      int col = t>>1, koff = (t&1)*32;
      #pragma unroll
      for (int j=0;j<4;j++){
        unsigned short tmp[8];
        #pragma unroll
        for (int q=0;q<8;q++) tmp[q] = f2bf(Wf[(koff + j*8 + q)*128 + col]);
        *reinterpret_cast<uint4*>(&out[col*128 + half*64 + koff + j*8]) = *reinterpret_cast<const uint4*>(tmp);
      }
    }
    {
      int ce = t>>4;
      int h  = ce & 7;
      if (b < 3){
        const float* av = (ce < 8) ? (as_ + h*16) : (ad_ + h*16);
        float avr[16];
        #pragma unroll
        for (int c2=0;c2<16;c2++) avr[c2] = av[c2];
        #pragma unroll
        for (int i=0;i<4;i++){
          int kl = (t&15) + i*16;
          float s = 0.f;
          #pragma unroll
          for (int c2=0;c2<16;c2++) s += Wf[kl*128 + h*16 + c2]*avr[c2];
          out[(128+ce)*128 + half*64 + kl] = f2bf(s);
        }
      } else {
        #pragma unroll
        for (int i=0;i<4;i++){
          int kl = (t&15) + i*16;
          out[(128+ce)*128 + half*64 + kl] = 0;
        }
      }
    }
    __syncthreads();
  }
}

// =============== Wout prep: fp32 [128k][40] -> bf16 hi/lo [48 cols][128 k] ===============
__global__ __launch_bounds__(256) void k_prep_out(const float* __restrict__ Wout, unsigned short* __restrict__ dst){
  int t = threadIdx.x;
  for (int i=t; i<48*128; i+=256){
    int col = i>>7, k = i&127;
    float v = (col < 40) ? Wout[(size_t)k*40 + col] : 0.f;
    unsigned short hi = f2bf(v);
    float r = v - __uint_as_float(((unsigned)hi)<<16);
    dst[i] = hi;
    dst[48*128 + i] = f2bf(r);
  }
}

// =============== MFMA GEMM (no LDS): A[M,128]bf16 @ Bt[144,128]bf16 ===============
__global__ __launch_bounds__(256) void k_gemm(
    const unsigned short* __restrict__ A, const unsigned short* __restrict__ Bt,
    unsigned short* __restrict__ C, float* __restrict__ s_src, float* __restrict__ s_dst, int M)
{
  int t = threadIdx.x, lane = t & 63, w = t >> 6;
  int rA = lane & 15, g = lane >> 4;
  int r0 = blockIdx.x*128 + w*32;
  f32x4 z = {0.f,0.f,0.f,0.f};
  f32x4 acc[2][9];
  #pragma unroll
  for (int mf=0;mf<2;mf++)
    #pragma unroll
    for (int nf=0;nf<9;nf++) acc[mf][nf] = z;

  int rowc0 = min(r0 + rA,      M-1);
  int rowc1 = min(r0 + 16 + rA, M-1);
  #pragma unroll
  for (int ks=0; ks<4; ks++){
    int ko = ks*32 + g*8;
    bf16x8 a0 = *reinterpret_cast<const bf16x8*>(A + (size_t)rowc0*128 + ko);
    bf16x8 a1 = *reinterpret_cast<const bf16x8*>(A + (size_t)rowc1*128 + ko);
    #pragma unroll
    for (int nf=0;nf<9;nf++){
      bf16x8 bf_ = *reinterpret_cast<const bf16x8*>(Bt + (size_t)(nf*16+rA)*128 + ko);
      acc[0][nf] = __builtin_amdgcn_mfma_f32_16x16x32_bf16(a0, bf_, acc[0][nf], 0, 0, 0);
      acc[1][nf] = __builtin_amdgcn_mfma_f32_16x16x32_bf16(a1, bf_, acc[1][nf], 0, 0, 0);
    }
  }

  #pragma unroll
  for (int mf=0;mf<2;mf++){
    #pragma unroll
    for (int r=0;r<4;r++){
      int row = r0 + mf*16 + g*4 + r;
      if (row < M){
        #pragma unroll
        for (int nf=0;nf<8;nf++) C[(size_t)row*128 + nf*16 + rA] = f2bf(acc[mf][nf][r]);
        float sv_ = acc[mf][8][r];
        if (rA < 8) s_src[(size_t)row*8 + rA]     = sv_;
        else        s_dst[(size_t)row*8 + rA - 8] = sv_;
      }
    }
  }
}

// =============== wave-per-node softmax-aggregate (16 lanes/row, uint4 gather) ===============
__global__ __launch_bounds__(256) void k_aggregate(
    const int* __restrict__ off, const int* __restrict__ csr,
    const unsigned short* __restrict__ htmp, const float* __restrict__ s_src,
    const float* __restrict__ s_dst, const float* __restrict__ bias,
    unsigned short* __restrict__ hout, int N_)
{
  __shared__ float esc[4][576];   // [head*72 + edge], pads 64..71 zeroed
  __shared__ int   ssrc[4][72];
  int w = threadIdx.x >> 6;
  int lane = threadIdx.x & 63;
  int n = blockIdx.x*4 + w;
  if (n >= N_) return;
  int base = off[n];
  int deg  = off[n+1] - base;
  int c2 = lane & 15;       // 16B chunk of the 256B row (8 channels = 1 head)
  int eo = lane >> 4;       // 0..3 edge offset
  int myh = c2 >> 1;        // head of my channels
  float4 sd0 = ld4(&s_dst[(size_t)n*8]);
  float4 sd1 = ld4(&s_dst[(size_t)n*8+4]);
  float sdv[8] = {sd0.x,sd0.y,sd0.z,sd0.w,sd1.x,sd1.y,sd1.z,sd1.w};
  float acc0=0.f,acc1=0.f,acc2=0.f,acc3=0.f,acc4=0.f,acc5=0.f,acc6=0.f,acc7=0.f;
  float dsum = 0.f;
  const char* hb = (const char*)htmp + (c2<<4);

  // zero LDS pads (edges 64..71) once
  ssrc[w][64 + (lane&7)] = 0;
  esc[w][(lane>>3)*72 + 64 + (lane&7)] = 0.f;

  for (int cb=0; cb<deg; cb+=64){
    int cdeg = min(64, deg-cb);
    int srcj = 0;
    float ee[8];
    if (lane < cdeg){
      srcj = csr[base+cb+lane];
      float4 a0 = ld4(&s_src[(size_t)srcj*8]);
      float4 a1 = ld4(&s_src[(size_t)srcj*8+4]);
      float sv[8] = {a0.x,a0.y,a0.z,a0.w,a1.x,a1.y,a1.z,a1.w};
      #pragma unroll
      for (int h=0;h<8;h++){
        float v = sv[h] + sdv[h];
        v = v > 0.f ? v : 0.2f*v;
        ee[h] = __expf(v);
      }
    } else {
      #pragma unroll
      for (int h=0;h<8;h++) ee[h] = 0.f;
    }
    ssrc[w][lane] = srcj;
    #pragma unroll
    for (int h=0;h<8;h++) esc[w][h*72 + lane] = ee[h];
    asm volatile("s_waitcnt lgkmcnt(0)" ::: "memory");
    __builtin_amdgcn_sched_barrier(0);

    for (int j=0; j<cdeg; j+=8){
      int e0 = j + eo;
      int e1 = j + 4 + eo;
      int s0 = ssrc[w][e0];
      int s1 = ssrc[w][e1];
      float ev0 = esc[w][myh*72 + e0];
      float ev1 = esc[w][myh*72 + e1];
      uint4 u0 = *reinterpret_cast<const uint4*>(hb + ((size_t)(unsigned)s0<<8));
      uint4 u1 = *reinterpret_cast<const uint4*>(hb + ((size_t)(unsigned)s1<<8));
      acc0 = fmaf(ev0, bflo(u0.x), acc0);
      acc1 = fmaf(ev0, bfhi(u0.x), acc1);
      acc2 = fmaf(ev0, bflo(u0.y), acc2);
      acc3 = fmaf(ev0, bfhi(u0.y), acc3);
      acc4 = fmaf(ev0, bflo(u0.z), acc4);
      acc5 = fmaf(ev0, bfhi(u0.z), acc5);
      acc6 = fmaf(ev0, bflo(u0.w), acc6);
      acc7 = fmaf(ev0, bfhi(u0.w), acc7);
      acc0 = fmaf(ev1, bflo(u1.x), acc0);
      acc1 = fmaf(ev1, bfhi(u1.x), acc1);
      acc2 = fmaf(ev1, bflo(u1.y), acc2);
      acc3 = fmaf(ev1, bfhi(u1.y), acc3);
      acc4 = fmaf(ev1, bflo(u1.z), acc4);
      acc5 = fmaf(ev1, bfhi(u1.z), acc5);
      acc6 = fmaf(ev1, bflo(u1.w), acc6);
      acc7 = fmaf(ev1, bfhi(u1.w), acc7);
      dsum += ev0 + ev1;
    }
  }
  // merge the 4 edge-offset groups (lanes with same c2)
  acc0 += __shfl_xor(acc0, 16); acc0 += __shfl_xor(acc0, 32);
  acc1 += __shfl_xor(acc1, 16); acc1 += __shfl_xor(acc1, 32);
  acc2 += __shfl_xor(acc2, 16); acc2 += __shfl_xor(acc2, 32);
  acc3 += __shfl_xor(acc3, 16); acc3 += __shfl_xor(acc3, 32);
  acc4 += __shfl_xor(acc4, 16); acc4 += __shfl_xor(acc4, 32);
  acc5 += __shfl_xor(acc5, 16); acc5 += __shfl_xor(acc5, 32);
  acc6 += __shfl_xor(acc6, 16); acc6 += __shfl_xor(acc6, 32);
  acc7 += __shfl_xor(acc7, 16); acc7 += __shfl_xor(acc7, 32);
  dsum += __shfl_xor(dsum, 16); dsum += __shfl_xor(dsum, 32);

  if (eo == 0){
    float inv = 1.f/(dsum + 1e-16f);
    float4 b0 = ld4(&bias[c2*8]);
    float4 b1 = ld4(&bias[c2*8+4]);
    float o0 = fmaf(acc0, inv, b0.x);
    float o1 = fmaf(acc1, inv, b0.y);
    float o2 = fmaf(acc2, inv, b0.z);
    float o3 = fmaf(acc3, inv, b0.w);
    float o4 = fmaf(acc4, inv, b1.x);
    float o5 = fmaf(acc5, inv, b1.y);
    float o6 = fmaf(acc6, inv, b1.z);
    float o7 = fmaf(acc7, inv, b1.w);
    o0 = o0>0.f ? o0 : (__expf(o0)-1.f);
    o1 = o1>0.f ? o1 : (__expf(o1)-1.f);
    o2 = o2>0.f ? o2 : (__expf(o2)-1.f);
    o3 = o3>0.f ? o3 : (__expf(o3)-1.f);
    o4 = o4>0.f ? o4 : (__expf(o4)-1.f);
    o5 = o5>0.f ? o5 : (__expf(o5)-1.f);
    o6 = o6>0.f ? o6 : (__expf(o6)-1.f);
    o7 = o7>0.f ? o7 : (__expf(o7)-1.f);
    uint4 pk;
    pk.x = (unsigned)f2bf(o0) | ((unsigned)f2bf(o1)<<16);
    pk.y = (unsigned)f2bf(o2) | ((unsigned)f2bf(o3)<<16);
    pk.z = (unsigned)f2bf(o4) | ((unsigned)f2bf(o5)<<16);
    pk.w = (unsigned)f2bf(o6) | ((unsigned)f2bf(o7)<<16);
    *reinterpret_cast<uint4*>(&hout[(size_t)n*128 + c2*8]) = pk;
  }
}

// =============== fused final v4: A-frag preload + B-share across layers ===============
// NOTE: no min-waves clamp ((256,4) caused 64-VGPR cap -> 134 MB spill, rounds 5/6).
__global__ __launch_bounds__(256) void k_final4(
    const unsigned short* __restrict__ h0, const unsigned short* __restrict__ h1,
    const unsigned short* __restrict__ h2,
    const unsigned short* __restrict__ WattT, const float* __restrict__ aatt,
    const unsigned short* __restrict__ WoutT,  // [48][128] hi, then [48][128] lo
    const float* __restrict__ bout, float* __restrict__ out, int M)
{
  int t = threadIdx.x, lane = t & 63, w = t >> 6;
  int rA = lane & 15, g = lane >> 4;
  int r0 = blockIdx.x*64 + w*16;
  int rowc = min(r0 + rA, M-1);

  float av[8];
  #pragma unroll
  for (int nf=0;nf<8;nf++) av[nf] = aatt[nf*16 + rA];

  // ---- preload A fragments for all 3 layers (reused in both passes) ----
  bf16x8 a[3][4];
  #pragma unroll
  for (int ks=0;ks<4;ks++){
    int ko = ks*32 + g*8;
    a[0][ks] = *reinterpret_cast<const bf16x8*>(h0 + (size_t)rowc*128 + ko);
    a[1][ks] = *reinterpret_cast<const bf16x8*>(h1 + (size_t)rowc*128 + ko);
    a[2][ks] = *reinterpret_cast<const bf16x8*>(h2 + (size_t)rowc*128 + ko);
  }

  // ---- pass 1: layer scores; B loaded once per (ch,ks,half), shared by 3 layers ----
  float sc[3][4];
  #pragma unroll
  for (int l=0;l<3;l++)
    #pragma unroll
    for (int r=0;r<4;r++) sc[l][r] = 0.f;

  #pragma unroll
  for (int ch=0; ch<4; ch++){
    f32x4 acc[3][2];
    #pragma unroll
    for (int l=0;l<3;l++){ acc[l][0] = (f32x4){0.f,0.f,0.f,0.f}; acc[l][1] = (f32x4){0.f,0.f,0.f,0.f}; }
    #pragma unroll
    for (int ks=0; ks<4; ks++){
      int ko = ks*32 + g*8;
      bf16x8 b0 = *reinterpret_cast<const bf16x8*>(WattT + (size_t)((ch*2+0)*16+rA)*128 + ko);
      bf16x8 b1 = *reinterpret_cast<const bf16x8*>(WattT + (size_t)((ch*2+1)*16+rA)*128 + ko);
      #pragma unroll
      for (int l=0;l<3;l++){
        acc[l][0] = __builtin_amdgcn_mfma_f32_16x16x32_bf16(a[l][ks], b0, acc[l][0], 0, 0, 0);
        acc[l][1] = __builtin_amdgcn_mfma_f32_16x16x32_bf16(a[l][ks], b1, acc[l][1], 0, 0, 0);
      }
    }
    float w0 = av[ch*2], w1 = av[ch*2+1];
    #pragma unroll
    for (int l=0;l<3;l++)
      #pragma unroll
      for (int r=0;r<4;r++)
        sc[l][r] += ftanh(acc[l][0][r])*w0 + ftanh(acc[l][1][r])*w1;
  }
  #pragma unroll
  for (int l=0;l<3;l++)
    #pragma unroll
    for (int r=0;r<4;r++){
      float s = sc[l][r];
      s += __shfl_xor(s, 1);
      s += __shfl_xor(s, 2);
      s += __shfl_xor(s, 4);
      s += __shfl_xor(s, 8);
      sc[l][r] = s;
    }

  // ---- layer softmax (in-register, all lanes) ----
  float lam[3][4];
  #pragma unroll
  for (int r=0;r<4;r++){
    float m = fmaxf(sc[0][r], fmaxf(sc[1][r], sc[2][r]));
    float e0 = __expf(sc[0][r]-m), e1 = __expf(sc[1][r]-m), e2 = __expf(sc[2][r]-m);
    float inv = 1.f/(e0+e1+e2);
    lam[0][r]=e0*inv; lam[1][r]=e1*inv; lam[2][r]=e2*inv;
  }
  // fetch lam for A-fragment row rA: source lane ((rA>>2)<<4)|rA holds it at r=rA&3
  int rsel = rA & 3;
  int srcLane = ((rA>>2)<<4) | rA;
  float p0 = rsel==0 ? lam[0][0] : rsel==1 ? lam[0][1] : rsel==2 ? lam[0][2] : lam[0][3];
  float p1 = rsel==0 ? lam[1][0] : rsel==1 ? lam[1][1] : rsel==2 ? lam[1][2] : lam[1][3];
  float p2 = rsel==0 ? lam[2][0] : rsel==1 ? lam[2][1] : rsel==2 ? lam[2][2] : lam[2][3];
  float lamA[3];
  lamA[0] = __shfl(p0, srcLane);
  lamA[1] = __shfl(p1, srcLane);
  lamA[2] = __shfl(p2, srcLane);

  // ---- pass 2: out = sum_l (lam_l * h_l) @ Wout (hi+lo); B loaded once per (ks,nf,half) ----
  f32x4 oacc[3];
  #pragma unroll
  for (int nf=0;nf<3;nf++) oacc[nf] = (f32x4){0.f,0.f,0.f,0.f};
  #pragma unroll
  for (int ks=0;ks<4;ks++){
    int ko = ks*32 + g*8;
    bf16x8 asc[3];
    #pragma unroll
    for (int l=0;l<3;l++){
      #pragma unroll
      for (int i=0;i<8;i++) asc[l][i] = (short)f2bf(bfs(a[l][ks][i]) * lamA[l]);
    }
    #pragma unroll
    for (int nf=0;nf<3;nf++){
      bf16x8 bh = *reinterpret_cast<const bf16x8*>(WoutT + (size_t)(nf*16+rA)*128 + ko);
      bf16x8 bl = *reinterpret_cast<const bf16x8*>(WoutT + 6144 + (size_t)(nf*16+rA)*128 + ko);
      #pragma unroll
      for (int l=0;l<3;l++){
        oacc[nf] = __builtin_amdgcn_mfma_f32_16x16x32_bf16(asc[l], bh, oacc[nf], 0, 0, 0);
        oacc[nf] = __builtin_amdgcn_mfma_f32_16x16x32_bf16(asc[l], bl, oacc[nf], 0, 0, 0);
      }
    }
  }

  #pragma unroll
  for (int nf=0;nf<3;nf++){
    int col = nf*16 + rA;
    float bv = (col < 40) ? bout[col] : 0.f;
    #pragma unroll
    for (int r=0;r<4;r++){
      int row = r0 + g*4 + r;
      if (row < M && col < 40) out[(size_t)row*40 + col] = oacc[nf][r] + bv;
    }
  }
}

extern "C" void kernel_launch(void* const* d_in, const int* in_sizes, int n_in,
                              void* d_out, int out_size, void* d_ws, size_t ws_size,
                              hipStream_t stream)
{
  const float* x    = (const float*)d_in[0];
  const int*   ei   = (const int*)d_in[1];
  const float* W0   = (const float*)d_in[2];
  const float* as0  = (const float*)d_in[3];
  const float* ad0  = (const float*)d_in[4];
  const float* b0   = (const float*)d_in[5];
  const float* W12  = (const float*)d_in[6];
  const float* as12 = (const float*)d_in[7];
  const float* ad12 = (const float*)d_in[8];
  const float* b12  = (const float*)d_in[9];
  const float* Watt = (const float*)d_in[10];
  const float* aatt = (const float*)d_in[11];
  const float* Wout = (const float*)d_in[12];
  const float* bout = (const float*)d_in[13];
  const int N_ = in_sizes[0] / 128;
  const int E_ = in_sizes[1] / 2;
  const int Et = E_ + N_;
  const int nb = (N_ + 1023) >> 10;

  char* p = (char*)d_ws;
  auto carve = [&](size_t bytes)->char*{ char* r = p; p += (bytes + 255) & ~(size_t)255; return r; };
  unsigned short* xb   = (unsigned short*)carve((size_t)N_*128*2);
  unsigned short* htmp = (unsigned short*)carve((size_t)N_*128*2);
  unsigned short* h0   = (unsigned short*)carve((size_t)N_*128*2);
  unsigned short* h1   = (unsigned short*)carve((size_t)N_*128*2);
  unsigned short* h2   = (unsigned short*)carve((size_t)N_*128*2);
  unsigned short* wsT  = (unsigned short*)carve((size_t)4*18432*2);
  unsigned short* woutT= (unsigned short*)carve((size_t)2*48*128*2);
  float* ssrc_s  = (float*)carve((size_t)N_*8*4);
  float* sdst_s  = (float*)carve((size_t)N_*8*4);
  int* cnt       = (int*)carve((size_t)N_*4);
  int* offv      = (int*)carve((size_t)(N_+1)*4);
  int* blk       = (int*)carve((size_t)64*4);
  int* blkoff    = (int*)carve((size_t)64*4);
  int* bcnt      = (int*)carve((size_t)64*4);
  int* bbase     = (int*)carve((size_t)66*4);
  int* bcursor   = (int*)carve((size_t)64*4);
  uint2* bdata   = (uint2*)carve((size_t)Et*8);
  int* csr       = (int*)carve((size_t)Et*4);

  k_prep<<<4,256,0,stream>>>(W0, W12, Watt, as0, ad0, as12, ad12, wsT);
  k_prep_out<<<1,256,0,stream>>>(Wout, woutT);
  k_xcast<<<(N_*128/8 + 255)/256,256,0,stream>>>(x, xb, N_*128/8);

  hipMemsetAsync(bcnt, 0, 64*4, stream);
  int gB = (Et + 2047)/2048;
  k_bcount<<<gB,256,0,stream>>>(ei, bcnt, E_, Et);
  k_binit<<<1,64,0,stream>>>(bcnt, bbase, bcursor, nb);
  k_bucket<<<gB,256,0,stream>>>(ei, bcursor, bdata, E_, Et);
  k_bhist<<<nb,512,0,stream>>>(bdata, bbase, cnt, N_);
  int nblk = (N_ + 1023)/1024;
  k_scan1<<<nblk,256,0,stream>>>(cnt, blk, N_);
  k_scan2<<<1,64,0,stream>>>(blk, blkoff, offv, N_, nblk);
  k_scan3<<<nblk,256,0,stream>>>(cnt, blkoff, offv, N_);
  k_bscatter<<<nb,512,0,stream>>>(bdata, bbase, offv, csr, N_);

  int gM  = (N_+127)/128;
  int gN4 = (N_+3)/4;
  int gF  = (N_+63)/64;
  unsigned short* hl[3] = {h0,h1,h2};
  const unsigned short* hin = xb;
  for (int l=0;l<3;l++){
    const float* bb = (l==0)? b0 : b12 + (size_t)(l-1)*128;
    const unsigned short* Bt = wsT + (size_t)l*18432;
    k_gemm<<<gM,256,0,stream>>>(hin, Bt, htmp, ssrc_s, sdst_s, N_);
    k_aggregate<<<gN4,256,0,stream>>>(offv, csr, htmp, ssrc_s, sdst_s, bb, hl[l], N_);
    hin = hl[l];
  }
  k_final4<<<gF,256,0,stream>>>(h0, h1, h2, wsT + (size_t)3*18432, aatt, woutT, bout, (float*)d_out, N_);
}

// Round 10
// 262.059 us; speedup vs baseline: 1.0888x; 1.0888x over previous
//
#include <hip/hip_runtime.h>
#include <hip/hip_bf16.h>

typedef float f32x4 __attribute__((ext_vector_type(4)));
typedef short bf16x8 __attribute__((ext_vector_type(8)));

#define BCAP 20480   // per-bucket capacity (mean 17408, +24 sigma)

__device__ __forceinline__ float4 ld4(const float* p){ return *reinterpret_cast<const float4*>(p); }
__device__ __forceinline__ unsigned short f2bf(float f){
  unsigned int u = __float_as_uint(f);
  u = (u + 0x7fffu + ((u>>16)&1u)) >> 16;
  return (unsigned short)u;
}
__device__ __forceinline__ float bflo(unsigned int u){ return __uint_as_float(u<<16); }
__device__ __forceinline__ float bfhi(unsigned int u){ return __uint_as_float(u & 0xffff0000u); }
__device__ __forceinline__ float bfs(short s){ return __uint_as_float(((unsigned)(unsigned short)s)<<16); }
__device__ __forceinline__ float ftanh(float x){
  float e = __expf(2.f*x);
  return fmaf(-2.f, __builtin_amdgcn_rcpf(e+1.f), 1.f);
}

// =============== CSR build: single-pass bucket + in-block scan ===============
__global__ __launch_bounds__(256) void k_bucket(const int* __restrict__ ei, int* __restrict__ bcnt,
                                                unsigned* __restrict__ bdata, int E_, int Et){
  __shared__ int h[64];
  __shared__ int base[64];
  int t = threadIdx.x;
  if (t < 64) h[t] = 0;
  __syncthreads();
  int e0 = blockIdx.x*2048 + t;
  int dv[8], sv[8], rv[8];
  #pragma unroll
  for (int k=0;k<8;k++){
    int e = e0 + k*256;
    if (e < Et){
      int s, d;
      if (e < E_){ s = ei[e]; d = ei[E_+e]; } else { s = e-E_; d = s; }
      dv[k] = d; sv[k] = s;
      rv[k] = atomicAdd(&h[d>>10], 1);
    } else dv[k] = -1;
  }
  __syncthreads();
  if (t < 64 && h[t]) base[t] = atomicAdd(&bcnt[t], h[t]);
  __syncthreads();
  #pragma unroll
  for (int k=0;k<8;k++){
    if (dv[k] >= 0){
      int b = dv[k]>>10;
      bdata[(size_t)b*BCAP + base[b] + rv[k]] = ((unsigned)(dv[k]&1023)<<17) | (unsigned)sv[k];
    }
  }
}

__global__ __launch_bounds__(64) void k_binit(const int* __restrict__ bcnt, int* __restrict__ bbase,
                                              int* __restrict__ off, int N_, int nb){
  int l = threadIdx.x;
  int v = (l < nb) ? bcnt[l] : 0;
  int incl = v;
  #pragma unroll
  for (int d=1; d<64; d<<=1){ int u = __shfl_up(incl, d); if (l>=d) incl += u; }
  if (l < nb) bbase[l] = incl - v;
  if (l == 63) off[N_] = incl;
}

// histogram of one bucket (1024 nodes) + in-block prefix scan -> off[]
__global__ __launch_bounds__(512) void k_bhist_scan(const unsigned* __restrict__ bdata,
                                                    const int* __restrict__ bcnt,
                                                    const int* __restrict__ bbase,
                                                    int* __restrict__ off, int N_){
  __shared__ int c[1024];
  __shared__ int wsum[8];
  int b = blockIdx.x, t = threadIdx.x;
  for (int i=t;i<1024;i+=512) c[i]=0;
  __syncthreads();
  size_t lo = (size_t)b*BCAP;
  size_t hi = lo + bcnt[b];
  for (size_t i=lo+t; i<hi; i+=512) atomicAdd(&c[bdata[i]>>17], 1);
  __syncthreads();
  int c0 = c[2*t], c1 = c[2*t+1];
  int s = c0 + c1;
  int lane = t&63, w = t>>6;
  int incl = s;
  #pragma unroll
  for (int d=1; d<64; d<<=1){ int u = __shfl_up(incl, d); if (lane>=d) incl += u; }
  if (lane==63) wsum[w] = incl;
  __syncthreads();
  int wpre = 0;
  #pragma unroll
  for (int k=0;k<8;k++) if (k<w) wpre += wsum[k];
  int run = bbase[b] + wpre + incl - s;
  int n = (b<<10) + 2*t;
  if (n   < N_) off[n]   = run;
  if (n+1 < N_) off[n+1] = run + c0;
}

__global__ __launch_bounds__(512) void k_bscatter(const unsigned* __restrict__ bdata,
                                                  const int* __restrict__ bcnt,
                                                  const int* __restrict__ off,
                                                  int* __restrict__ csr, int N_){
  __shared__ int cur[1024];
  int b = blockIdx.x, t = threadIdx.x;
  int n0 = b<<10;
  for (int i=t;i<1024;i+=512){ int n = n0+i; cur[i] = (n < N_) ? off[n] : 0; }
  __syncthreads();
  size_t lo = (size_t)b*BCAP;
  size_t hi = lo + bcnt[b];
  for (size_t i=lo+t; i<hi; i+=512){
    unsigned p = bdata[i];
    int pos = atomicAdd(&cur[p>>17], 1);
    csr[pos] = (int)(p & 0x1FFFFu);
  }
}

// =============== weight prep: blocks 0..3 -> Bt [144][128] bf16; block 4 -> Wout hi/lo ===============
__global__ __launch_bounds__(256) void k_prep(const float* __restrict__ W0, const float* __restrict__ W12,
    const float* __restrict__ Watt, const float* __restrict__ as0, const float* __restrict__ ad0,
    const float* __restrict__ as12, const float* __restrict__ ad12,
    const float* __restrict__ Wout, unsigned short* __restrict__ dst){
  int b = blockIdx.x, t = threadIdx.x;
  if (b == 4){
    unsigned short* wo = dst + (size_t)4*18432;
    for (int i=t; i<48*128; i+=256){
      int col = i>>7, k = i&127;
      float v = (col < 40) ? Wout[(size_t)k*40 + col] : 0.f;
      unsigned short hi = f2bf(v);
      float r = v - __uint_as_float(((unsigned)hi)<<16);
      wo[i] = hi;
      wo[48*128 + i] = f2bf(r);
    }
    return;
  }
  __shared__ float Wf[64*128];
  const float* W = (b==0) ? W0 : (b==3 ? Watt : W12 + (size_t)(b-1)*16384);
  unsigned short* out = dst + (size_t)b*18432;
  const float* as_ = (b==0) ? as0 : as12 + (size_t)(b-1)*128;
  const float* ad_ = (b==0) ? ad0 : ad12 + (size_t)(b-1)*128;

  for (int half=0; half<2; half++){
    #pragma unroll
    for (int p=0;p<8;p++){
      int i = p*256 + t;
      *reinterpret_cast<float4*>(&Wf[i*4]) = ld4(&W[(size_t)half*8192 + i*4]);
    }
    __syncthreads();
    {
      int col = t>>1, koff = (t&1)*32;
      #pragma unroll
      for (int j=0;j<4;j++){
        unsigned short tmp[8];
        #pragma unroll
        for (int q=0;q<8;q++) tmp[q] = f2bf(Wf[(koff + j*8 + q)*128 + col]);
        *reinterpret_cast<uint4*>(&out[col*128 + half*64 + koff + j*8]) = *reinterpret_cast<const uint4*>(tmp);
      }
    }
    {
      int ce = t>>4;
      int h  = ce & 7;
      if (b < 3){
        const float* av = (ce < 8) ? (as_ + h*16) : (ad_ + h*16);
        float avr[16];
        #pragma unroll
        for (int c2=0;c2<16;c2++) avr[c2] = av[c2];
        #pragma unroll
        for (int i=0;i<4;i++){
          int kl = (t&15) + i*16;
          float s = 0.f;
          #pragma unroll
          for (int c2=0;c2<16;c2++) s += Wf[kl*128 + h*16 + c2]*avr[c2];
          out[(128+ce)*128 + half*64 + kl] = f2bf(s);
        }
      } else {
        #pragma unroll
        for (int i=0;i<4;i++){
          int kl = (t&15) + i*16;
          out[(128+ce)*128 + half*64 + kl] = 0;
        }
      }
    }
    __syncthreads();
  }
}

// =============== MFMA GEMM (no LDS): A[M,128] @ Bt[144,128]bf16; AF32: A is fp32 ===============
template<int AF32>
__global__ __launch_bounds__(256) void k_gemm(
    const void* __restrict__ Ap, const unsigned short* __restrict__ Bt,
    unsigned short* __restrict__ C, float* __restrict__ s_src, float* __restrict__ s_dst, int M)
{
  int t = threadIdx.x, lane = t & 63, w = t >> 6;
  int rA = lane & 15, g = lane >> 4;
  int r0 = blockIdx.x*128 + w*32;
  f32x4 z = {0.f,0.f,0.f,0.f};
  f32x4 acc[2][9];
  #pragma unroll
  for (int mf=0;mf<2;mf++)
    #pragma unroll
    for (int nf=0;nf<9;nf++) acc[mf][nf] = z;

  int rowc0 = min(r0 + rA,      M-1);
  int rowc1 = min(r0 + 16 + rA, M-1);
  #pragma unroll
  for (int ks=0; ks<4; ks++){
    int ko = ks*32 + g*8;
    bf16x8 a0, a1;
    if (AF32){
      const float* Af = (const float*)Ap;
      float4 v0 = ld4(&Af[(size_t)rowc0*128 + ko]);
      float4 v1 = ld4(&Af[(size_t)rowc0*128 + ko + 4]);
      float4 v2 = ld4(&Af[(size_t)rowc1*128 + ko]);
      float4 v3 = ld4(&Af[(size_t)rowc1*128 + ko + 4]);
      a0[0]=(short)f2bf(v0.x); a0[1]=(short)f2bf(v0.y); a0[2]=(short)f2bf(v0.z); a0[3]=(short)f2bf(v0.w);
      a0[4]=(short)f2bf(v1.x); a0[5]=(short)f2bf(v1.y); a0[6]=(short)f2bf(v1.z); a0[7]=(short)f2bf(v1.w);
      a1[0]=(short)f2bf(v2.x); a1[1]=(short)f2bf(v2.y); a1[2]=(short)f2bf(v2.z); a1[3]=(short)f2bf(v2.w);
      a1[4]=(short)f2bf(v3.x); a1[5]=(short)f2bf(v3.y); a1[6]=(short)f2bf(v3.z); a1[7]=(short)f2bf(v3.w);
    } else {
      const unsigned short* A = (const unsigned short*)Ap;
      a0 = *reinterpret_cast<const bf16x8*>(A + (size_t)rowc0*128 + ko);
      a1 = *reinterpret_cast<const bf16x8*>(A + (size_t)rowc1*128 + ko);
    }
    #pragma unroll
    for (int nf=0;nf<9;nf++){
      bf16x8 bf_ = *reinterpret_cast<const bf16x8*>(Bt + (size_t)(nf*16+rA)*128 + ko);
      acc[0][nf] = __builtin_amdgcn_mfma_f32_16x16x32_bf16(a0, bf_, acc[0][nf], 0, 0, 0);
      acc[1][nf] = __builtin_amdgcn_mfma_f32_16x16x32_bf16(a1, bf_, acc[1][nf], 0, 0, 0);
    }
  }

  #pragma unroll
  for (int mf=0;mf<2;mf++){
    #pragma unroll
    for (int r=0;r<4;r++){
      int row = r0 + mf*16 + g*4 + r;
      if (row < M){
        #pragma unroll
        for (int nf=0;nf<8;nf++) C[(size_t)row*128 + nf*16 + rA] = f2bf(acc[mf][nf][r]);
        float sv_ = acc[mf][8][r];
        if (rA < 8) s_src[(size_t)row*8 + rA]     = sv_;
        else        s_dst[(size_t)row*8 + rA - 8] = sv_;
      }
    }
  }
}

// =============== wave-per-node softmax-aggregate (16 lanes/row, 4 gathers in flight) ===============
__global__ __launch_bounds__(256) void k_aggregate(
    const int* __restrict__ off, const int* __restrict__ csr,
    const unsigned short* __restrict__ htmp, const float* __restrict__ s_src,
    const float* __restrict__ s_dst, const float* __restrict__ bias,
    unsigned short* __restrict__ hout, int N_)
{
  __shared__ float esc[4][640];   // [head*80 + edge], pads 64..79 zeroed
  __shared__ int   ssrc[4][80];
  int w = threadIdx.x >> 6;
  int lane = threadIdx.x & 63;
  int n = blockIdx.x*4 + w;
  if (n >= N_) return;
  int base = off[n];
  int deg  = off[n+1] - base;
  int c2 = lane & 15;       // 16B chunk of the 256B row (8 channels = 1 head)
  int eo = lane >> 4;       // 0..3 edge offset
  int myh = c2 >> 1;        // head of my channels
  float4 sd0 = ld4(&s_dst[(size_t)n*8]);
  float4 sd1 = ld4(&s_dst[(size_t)n*8+4]);
  float sdv[8] = {sd0.x,sd0.y,sd0.z,sd0.w,sd1.x,sd1.y,sd1.z,sd1.w};
  float acc0=0.f,acc1=0.f,acc2=0.f,acc3=0.f,acc4=0.f,acc5=0.f,acc6=0.f,acc7=0.f;
  float dsum = 0.f;
  const char* hb = (const char*)htmp + (c2<<4);

  // zero LDS pads (edges 64..79) once
  ssrc[w][64 + (lane&15)] = 0;
  esc[w][(lane>>3)*80 + 64 + (lane&7)*2]     = 0.f;
  esc[w][(lane>>3)*80 + 64 + (lane&7)*2 + 1] = 0.f;

  for (int cb=0; cb<deg; cb+=64){
    int cdeg = min(64, deg-cb);
    int srcj = 0;
    float ee[8];
    if (lane < cdeg){
      srcj = csr[base+cb+lane];
      float4 a0 = ld4(&s_src[(size_t)srcj*8]);
      float4 a1 = ld4(&s_src[(size_t)srcj*8+4]);
      float sv[8] = {a0.x,a0.y,a0.z,a0.w,a1.x,a1.y,a1.z,a1.w};
      #pragma unroll
      for (int h=0;h<8;h++){
        float v = sv[h] + sdv[h];
        v = v > 0.f ? v : 0.2f*v;
        ee[h] = __expf(v);
      }
    } else {
      #pragma unroll
      for (int h=0;h<8;h++) ee[h] = 0.f;
    }
    ssrc[w][lane] = srcj;
    #pragma unroll
    for (int h=0;h<8;h++) esc[w][h*80 + lane] = ee[h];
    asm volatile("s_waitcnt lgkmcnt(0)" ::: "memory");
    __builtin_amdgcn_sched_barrier(0);

    for (int j=0; j<cdeg; j+=16){
      int e0 = j + eo;
      int e1 = j + 4 + eo;
      int e2 = j + 8 + eo;
      int e3 = j + 12 + eo;
      int s0 = ssrc[w][e0];
      int s1 = ssrc[w][e1];
      int s2 = ssrc[w][e2];
      int s3 = ssrc[w][e3];
      float ev0 = esc[w][myh*80 + e0];
      float ev1 = esc[w][myh*80 + e1];
      float ev2 = esc[w][myh*80 + e2];
      float ev3 = esc[w][myh*80 + e3];
      uint4 u0 = *reinterpret_cast<const uint4*>(hb + ((size_t)(unsigned)s0<<8));
      uint4 u1 = *reinterpret_cast<const uint4*>(hb + ((size_t)(unsigned)s1<<8));
      uint4 u2 = *reinterpret_cast<const uint4*>(hb + ((size_t)(unsigned)s2<<8));
      uint4 u3 = *reinterpret_cast<const uint4*>(hb + ((size_t)(unsigned)s3<<8));
      acc0 = fmaf(ev0, bflo(u0.x), acc0);
      acc1 = fmaf(ev0, bfhi(u0.x), acc1);
      acc2 = fmaf(ev0, bflo(u0.y), acc2);
      acc3 = fmaf(ev0, bfhi(u0.y), acc3);
      acc4 = fmaf(ev0, bflo(u0.z), acc4);
      acc5 = fmaf(ev0, bfhi(u0.z), acc5);
      acc6 = fmaf(ev0, bflo(u0.w), acc6);
      acc7 = fmaf(ev0, bfhi(u0.w), acc7);
      acc0 = fmaf(ev1, bflo(u1.x), acc0);
      acc1 = fmaf(ev1, bfhi(u1.x), acc1);
      acc2 = fmaf(ev1, bflo(u1.y), acc2);
      acc3 = fmaf(ev1, bfhi(u1.y), acc3);
      acc4 = fmaf(ev1, bflo(u1.z), acc4);
      acc5 = fmaf(ev1, bfhi(u1.z), acc5);
      acc6 = fmaf(ev1, bflo(u1.w), acc6);
      acc7 = fmaf(ev1, bfhi(u1.w), acc7);
      acc0 = fmaf(ev2, bflo(u2.x), acc0);
      acc1 = fmaf(ev2, bfhi(u2.x), acc1);
      acc2 = fmaf(ev2, bflo(u2.y), acc2);
      acc3 = fmaf(ev2, bfhi(u2.y), acc3);
      acc4 = fmaf(ev2, bflo(u2.z), acc4);
      acc5 = fmaf(ev2, bfhi(u2.z), acc5);
      acc6 = fmaf(ev2, bflo(u2.w), acc6);
      acc7 = fmaf(ev2, bfhi(u2.w), acc7);
      acc0 = fmaf(ev3, bflo(u3.x), acc0);
      acc1 = fmaf(ev3, bfhi(u3.x), acc1);
      acc2 = fmaf(ev3, bflo(u3.y), acc2);
      acc3 = fmaf(ev3, bfhi(u3.y), acc3);
      acc4 = fmaf(ev3, bflo(u3.z), acc4);
      acc5 = fmaf(ev3, bfhi(u3.z), acc5);
      acc6 = fmaf(ev3, bflo(u3.w), acc6);
      acc7 = fmaf(ev3, bfhi(u3.w), acc7);
      dsum += (ev0 + ev1) + (ev2 + ev3);
    }
  }
  // merge the 4 edge-offset groups (lanes with same c2)
  acc0 += __shfl_xor(acc0, 16); acc0 += __shfl_xor(acc0, 32);
  acc1 += __shfl_xor(acc1, 16); acc1 += __shfl_xor(acc1, 32);
  acc2 += __shfl_xor(acc2, 16); acc2 += __shfl_xor(acc2, 32);
  acc3 += __shfl_xor(acc3, 16); acc3 += __shfl_xor(acc3, 32);
  acc4 += __shfl_xor(acc4, 16); acc4 += __shfl_xor(acc4, 32);
  acc5 += __shfl_xor(acc5, 16); acc5 += __shfl_xor(acc5, 32);
  acc6 += __shfl_xor(acc6, 16); acc6 += __shfl_xor(acc6, 32);
  acc7 += __shfl_xor(acc7, 16); acc7 += __shfl_xor(acc7, 32);
  dsum += __shfl_xor(dsum, 16); dsum += __shfl_xor(dsum, 32);

  if (eo == 0){
    float inv = 1.f/(dsum + 1e-16f);
    float4 b0 = ld4(&bias[c2*8]);
    float4 b1 = ld4(&bias[c2*8+4]);
    float o0 = fmaf(acc0, inv, b0.x);
    float o1 = fmaf(acc1, inv, b0.y);
    float o2 = fmaf(acc2, inv, b0.z);
    float o3 = fmaf(acc3, inv, b0.w);
    float o4 = fmaf(acc4, inv, b1.x);
    float o5 = fmaf(acc5, inv, b1.y);
    float o6 = fmaf(acc6, inv, b1.z);
    float o7 = fmaf(acc7, inv, b1.w);
    o0 = o0>0.f ? o0 : (__expf(o0)-1.f);
    o1 = o1>0.f ? o1 : (__expf(o1)-1.f);
    o2 = o2>0.f ? o2 : (__expf(o2)-1.f);
    o3 = o3>0.f ? o3 : (__expf(o3)-1.f);
    o4 = o4>0.f ? o4 : (__expf(o4)-1.f);
    o5 = o5>0.f ? o5 : (__expf(o5)-1.f);
    o6 = o6>0.f ? o6 : (__expf(o6)-1.f);
    o7 = o7>0.f ? o7 : (__expf(o7)-1.f);
    uint4 pk;
    pk.x = (unsigned)f2bf(o0) | ((unsigned)f2bf(o1)<<16);
    pk.y = (unsigned)f2bf(o2) | ((unsigned)f2bf(o3)<<16);
    pk.z = (unsigned)f2bf(o4) | ((unsigned)f2bf(o5)<<16);
    pk.w = (unsigned)f2bf(o6) | ((unsigned)f2bf(o7)<<16);
    *reinterpret_cast<uint4*>(&hout[(size_t)n*128 + c2*8]) = pk;
  }
}

// =============== fused final v4: A-frag preload + B-share across layers ===============
// NOTE: no min-waves clamp ((256,4) caused 64-VGPR cap -> 134 MB spill, rounds 5/6).
__global__ __launch_bounds__(256) void k_final4(
    const unsigned short* __restrict__ h0, const unsigned short* __restrict__ h1,
    const unsigned short* __restrict__ h2,
    const unsigned short* __restrict__ WattT, const float* __restrict__ aatt,
    const unsigned short* __restrict__ WoutT,  // [48][128] hi, then [48][128] lo
    const float* __restrict__ bout, float* __restrict__ out, int M)
{
  int t = threadIdx.x, lane = t & 63, w = t >> 6;
  int rA = lane & 15, g = lane >> 4;
  int r0 = blockIdx.x*64 + w*16;
  int rowc = min(r0 + rA, M-1);

  float av[8];
  #pragma unroll
  for (int nf=0;nf<8;nf++) av[nf] = aatt[nf*16 + rA];

  bf16x8 a[3][4];
  #pragma unroll
  for (int ks=0;ks<4;ks++){
    int ko = ks*32 + g*8;
    a[0][ks] = *reinterpret_cast<const bf16x8*>(h0 + (size_t)rowc*128 + ko);
    a[1][ks] = *reinterpret_cast<const bf16x8*>(h1 + (size_t)rowc*128 + ko);
    a[2][ks] = *reinterpret_cast<const bf16x8*>(h2 + (size_t)rowc*128 + ko);
  }

  float sc[3][4];
  #pragma unroll
  for (int l=0;l<3;l++)
    #pragma unroll
    for (int r=0;r<4;r++) sc[l][r] = 0.f;

  #pragma unroll
  for (int ch=0; ch<4; ch++){
    f32x4 acc[3][2];
    #pragma unroll
    for (int l=0;l<3;l++){ acc[l][0] = (f32x4){0.f,0.f,0.f,0.f}; acc[l][1] = (f32x4){0.f,0.f,0.f,0.f}; }
    #pragma unroll
    for (int ks=0; ks<4; ks++){
      int ko = ks*32 + g*8;
      bf16x8 b0 = *reinterpret_cast<const bf16x8*>(WattT + (size_t)((ch*2+0)*16+rA)*128 + ko);
      bf16x8 b1 = *reinterpret_cast<const bf16x8*>(WattT + (size_t)((ch*2+1)*16+rA)*128 + ko);
      #pragma unroll
      for (int l=0;l<3;l++){
        acc[l][0] = __builtin_amdgcn_mfma_f32_16x16x32_bf16(a[l][ks], b0, acc[l][0], 0, 0, 0);
        acc[l][1] = __builtin_amdgcn_mfma_f32_16x16x32_bf16(a[l][ks], b1, acc[l][1], 0, 0, 0);
      }
    }
    float w0 = av[ch*2], w1 = av[ch*2+1];
    #pragma unroll
    for (int l=0;l<3;l++)
      #pragma unroll
      for (int r=0;r<4;r++)
        sc[l][r] += ftanh(acc[l][0][r])*w0 + ftanh(acc[l][1][r])*w1;
  }
  #pragma unroll
  for (int l=0;l<3;l++)
    #pragma unroll
    for (int r=0;r<4;r++){
      float s = sc[l][r];
      s += __shfl_xor(s, 1);
      s += __shfl_xor(s, 2);
      s += __shfl_xor(s, 4);
      s += __shfl_xor(s, 8);
      sc[l][r] = s;
    }

  float lam[3][4];
  #pragma unroll
  for (int r=0;r<4;r++){
    float m = fmaxf(sc[0][r], fmaxf(sc[1][r], sc[2][r]));
    float e0 = __expf(sc[0][r]-m), e1 = __expf(sc[1][r]-m), e2 = __expf(sc[2][r]-m);
    float inv = 1.f/(e0+e1+e2);
    lam[0][r]=e0*inv; lam[1][r]=e1*inv; lam[2][r]=e2*inv;
  }
  int rsel = rA & 3;
  int srcLane = ((rA>>2)<<4) | rA;
  float p0 = rsel==0 ? lam[0][0] : rsel==1 ? lam[0][1] : rsel==2 ? lam[0][2] : lam[0][3];
  float p1 = rsel==0 ? lam[1][0] : rsel==1 ? lam[1][1] : rsel==2 ? lam[1][2] : lam[1][3];
  float p2 = rsel==0 ? lam[2][0] : rsel==1 ? lam[2][1] : rsel==2 ? lam[2][2] : lam[2][3];
  float lamA[3];
  lamA[0] = __shfl(p0, srcLane);
  lamA[1] = __shfl(p1, srcLane);
  lamA[2] = __shfl(p2, srcLane);

  f32x4 oacc[3];
  #pragma unroll
  for (int nf=0;nf<3;nf++) oacc[nf] = (f32x4){0.f,0.f,0.f,0.f};
  #pragma unroll
  for (int ks=0;ks<4;ks++){
    int ko = ks*32 + g*8;
    bf16x8 asc[3];
    #pragma unroll
    for (int l=0;l<3;l++){
      #pragma unroll
      for (int i=0;i<8;i++) asc[l][i] = (short)f2bf(bfs(a[l][ks][i]) * lamA[l]);
    }
    #pragma unroll
    for (int nf=0;nf<3;nf++){
      bf16x8 bh = *reinterpret_cast<const bf16x8*>(WoutT + (size_t)(nf*16+rA)*128 + ko);
      bf16x8 bl = *reinterpret_cast<const bf16x8*>(WoutT + 6144 + (size_t)(nf*16+rA)*128 + ko);
      #pragma unroll
      for (int l=0;l<3;l++){
        oacc[nf] = __builtin_amdgcn_mfma_f32_16x16x32_bf16(asc[l], bh, oacc[nf], 0, 0, 0);
        oacc[nf] = __builtin_amdgcn_mfma_f32_16x16x32_bf16(asc[l], bl, oacc[nf], 0, 0, 0);
      }
    }
  }

  #pragma unroll
  for (int nf=0;nf<3;nf++){
    int col = nf*16 + rA;
    float bv = (col < 40) ? bout[col] : 0.f;
    #pragma unroll
    for (int r=0;r<4;r++){
      int row = r0 + g*4 + r;
      if (row < M && col < 40) out[(size_t)row*40 + col] = oacc[nf][r] + bv;
    }
  }
}

extern "C" void kernel_launch(void* const* d_in, const int* in_sizes, int n_in,
                              void* d_out, int out_size, void* d_ws, size_t ws_size,
                              hipStream_t stream)
{
  const float* x    = (const float*)d_in[0];
  const int*   ei   = (const int*)d_in[1];
  const float* W0   = (const float*)d_in[2];
  const float* as0  = (const float*)d_in[3];
  const float* ad0  = (const float*)d_in[4];
  const float* b0   = (const float*)d_in[5];
  const float* W12  = (const float*)d_in[6];
  const float* as12 = (const float*)d_in[7];
  const float* ad12 = (const float*)d_in[8];
  const float* b12  = (const float*)d_in[9];
  const float* Watt = (const float*)d_in[10];
  const float* aatt = (const float*)d_in[11];
  const float* Wout = (const float*)d_in[12];
  const float* bout = (const float*)d_in[13];
  const int N_ = in_sizes[0] / 128;
  const int E_ = in_sizes[1] / 2;
  const int Et = E_ + N_;
  const int nb = (N_ + 1023) >> 10;

  char* p = (char*)d_ws;
  auto carve = [&](size_t bytes)->char*{ char* r = p; p += (bytes + 255) & ~(size_t)255; return r; };
  unsigned short* htmp = (unsigned short*)carve((size_t)N_*128*2);
  unsigned short* h0   = (unsigned short*)carve((size_t)N_*128*2);
  unsigned short* h1   = (unsigned short*)carve((size_t)N_*128*2);
  unsigned short* h2   = (unsigned short*)carve((size_t)N_*128*2);
  unsigned short* wsT  = (unsigned short*)carve((size_t)(5*18432 + 48*128)*2);
  float* ssrc_s  = (float*)carve((size_t)N_*8*4);
  float* sdst_s  = (float*)carve((size_t)N_*8*4);
  int* offv      = (int*)carve((size_t)(N_+1)*4);
  int* bcnt      = (int*)carve((size_t)64*4);
  int* bbase     = (int*)carve((size_t)64*4);
  unsigned* bdata= (unsigned*)carve((size_t)64*BCAP*4);
  int* csr       = (int*)carve((size_t)Et*4);

  k_prep<<<5,256,0,stream>>>(W0, W12, Watt, as0, ad0, as12, ad12, Wout, wsT);

  hipMemsetAsync(bcnt, 0, 64*4, stream);
  int gB = (Et + 2047)/2048;
  k_bucket<<<gB,256,0,stream>>>(ei, bcnt, bdata, E_, Et);
  k_binit<<<1,64,0,stream>>>(bcnt, bbase, offv, N_, nb);
  k_bhist_scan<<<nb,512,0,stream>>>(bdata, bcnt, bbase, offv, N_);
  k_bscatter<<<nb,512,0,stream>>>(bdata, bcnt, offv, csr, N_);

  int gM  = (N_+127)/128;
  int gN4 = (N_+3)/4;
  int gF  = (N_+63)/64;
  unsigned short* hl[3] = {h0,h1,h2};
  for (int l=0;l<3;l++){
    const float* bb = (l==0)? b0 : b12 + (size_t)(l-1)*128;
    const unsigned short* Bt = wsT + (size_t)l*18432;
    if (l==0)
      k_gemm<1><<<gM,256,0,stream>>>((const void*)x, Bt, htmp, ssrc_s, sdst_s, N_);
    else
      k_gemm<0><<<gM,256,0,stream>>>((const void*)hl[l-1], Bt, htmp, ssrc_s, sdst_s, N_);
    k_aggregate<<<gN4,256,0,stream>>>(offv, csr, htmp, ssrc_s, sdst_s, bb, hl[l], N_);
  }
  k_final4<<<gF,256,0,stream>>>(h0, h1, h2, wsT + (size_t)3*18432, aatt,
                                wsT + (size_t)4*18432, bout, (float*)d_out, N_);
}

// Round 11
// 246.901 us; speedup vs baseline: 1.1556x; 1.0614x over previous
//
#include <hip/hip_runtime.h>
#include <hip/hip_bf16.h>

typedef float f32x4 __attribute__((ext_vector_type(4)));
typedef short bf16x8 __attribute__((ext_vector_type(8)));

#define BCAP 20480   // per-bucket capacity (mean 17408, +24 sigma)

__device__ __forceinline__ float4 ld4(const float* p){ return *reinterpret_cast<const float4*>(p); }
__device__ __forceinline__ unsigned short f2bf(float f){
  unsigned int u = __float_as_uint(f);
  u = (u + 0x7fffu + ((u>>16)&1u)) >> 16;
  return (unsigned short)u;
}
__device__ __forceinline__ float bflo(unsigned int u){ return __uint_as_float(u<<16); }
__device__ __forceinline__ float bfhi(unsigned int u){ return __uint_as_float(u & 0xffff0000u); }
__device__ __forceinline__ float bfs(short s){ return __uint_as_float(((unsigned)(unsigned short)s)<<16); }
__device__ __forceinline__ float ftanh(float x){
  float e = __expf(2.f*x);
  return fmaf(-2.f, __builtin_amdgcn_rcpf(e+1.f), 1.f);
}

// =============== CSR build: single-pass bucket ===============
__global__ __launch_bounds__(256) void k_bucket(const int* __restrict__ ei, int* __restrict__ bcnt,
                                                unsigned* __restrict__ bdata, int E_, int Et){
  __shared__ int h[64];
  __shared__ int base[64];
  int t = threadIdx.x;
  if (t < 64) h[t] = 0;
  __syncthreads();
  int e0 = blockIdx.x*2048 + t;
  int dv[8], sv[8], rv[8];
  #pragma unroll
  for (int k=0;k<8;k++){
    int e = e0 + k*256;
    if (e < Et){
      int s, d;
      if (e < E_){ s = ei[e]; d = ei[E_+e]; } else { s = e-E_; d = s; }
      dv[k] = d; sv[k] = s;
      rv[k] = atomicAdd(&h[d>>10], 1);
    } else dv[k] = -1;
  }
  __syncthreads();
  if (t < 64 && h[t]) base[t] = atomicAdd(&bcnt[t], h[t]);
  __syncthreads();
  #pragma unroll
  for (int k=0;k<8;k++){
    if (dv[k] >= 0){
      int b = dv[k]>>10;
      bdata[(size_t)b*BCAP + base[b] + rv[k]] = ((unsigned)(dv[k]&1023)<<17) | (unsigned)sv[k];
    }
  }
}

__global__ __launch_bounds__(64) void k_binit(const int* __restrict__ bcnt, int* __restrict__ bbase,
                                              int* __restrict__ off, int N_, int nb){
  int l = threadIdx.x;
  int v = (l < nb) ? bcnt[l] : 0;
  int incl = v;
  #pragma unroll
  for (int d=1; d<64; d<<=1){ int u = __shfl_up(incl, d); if (l>=d) incl += u; }
  if (l < nb) bbase[l] = incl - v;
  if (l == 63) off[N_] = incl;
}

// hist + in-block scan + scatter, all in one kernel (cursor = reused LDS hist)
__global__ __launch_bounds__(512) void k_bfinish(const unsigned* __restrict__ bdata,
                                                 const int* __restrict__ bcnt,
                                                 const int* __restrict__ bbase,
                                                 int* __restrict__ off, int* __restrict__ csr, int N_){
  __shared__ int c[1024];
  __shared__ int wsum[8];
  int b = blockIdx.x, t = threadIdx.x;
  int cnt = bcnt[b];
  size_t lo = (size_t)b*BCAP;
  for (int i=t;i<1024;i+=512) c[i]=0;
  __syncthreads();
  for (int i=t; i<cnt; i+=512) atomicAdd(&c[bdata[lo+i]>>17], 1);
  __syncthreads();
  int c0 = c[2*t], c1 = c[2*t+1];
  int s = c0 + c1;
  int lane = t&63, w = t>>6;
  int incl = s;
  #pragma unroll
  for (int d=1; d<64; d<<=1){ int u = __shfl_up(incl, d); if (lane>=d) incl += u; }
  if (lane==63) wsum[w] = incl;
  __syncthreads();
  int wpre = 0;
  #pragma unroll
  for (int k=0;k<8;k++) if (k<w) wpre += wsum[k];
  int run = bbase[b] + wpre + incl - s;
  int n = (b<<10) + 2*t;
  if (n   < N_) off[n]   = run;
  if (n+1 < N_) off[n+1] = run + c0;
  // reuse c as scatter cursors
  c[2*t]   = run;
  c[2*t+1] = run + c0;
  __syncthreads();
  for (int i=t; i<cnt; i+=512){
    unsigned p = bdata[lo+i];
    int pos = atomicAdd(&c[p>>17], 1);
    csr[pos] = (int)(p & 0x1FFFFu);
  }
}

// =============== weight prep: blocks 0..3 -> Bt [144][128] bf16; block 4 -> Wout hi/lo ===============
__global__ __launch_bounds__(256) void k_prep(const float* __restrict__ W0, const float* __restrict__ W12,
    const float* __restrict__ Watt, const float* __restrict__ as0, const float* __restrict__ ad0,
    const float* __restrict__ as12, const float* __restrict__ ad12,
    const float* __restrict__ Wout, unsigned short* __restrict__ dst){
  int b = blockIdx.x, t = threadIdx.x;
  if (b == 4){
    unsigned short* wo = dst + (size_t)4*18432;
    for (int i=t; i<48*128; i+=256){
      int col = i>>7, k = i&127;
      float v = (col < 40) ? Wout[(size_t)k*40 + col] : 0.f;
      unsigned short hi = f2bf(v);
      float r = v - __uint_as_float(((unsigned)hi)<<16);
      wo[i] = hi;
      wo[48*128 + i] = f2bf(r);
    }
    return;
  }
  __shared__ float Wf[64*128];
  const float* W = (b==0) ? W0 : (b==3 ? Watt : W12 + (size_t)(b-1)*16384);
  unsigned short* out = dst + (size_t)b*18432;
  const float* as_ = (b==0) ? as0 : as12 + (size_t)(b-1)*128;
  const float* ad_ = (b==0) ? ad0 : ad12 + (size_t)(b-1)*128;

  for (int half=0; half<2; half++){
    #pragma unroll
    for (int p=0;p<8;p++){
      int i = p*256 + t;
      *reinterpret_cast<float4*>(&Wf[i*4]) = ld4(&W[(size_t)half*8192 + i*4]);
    }
    __syncthreads();
    {
      int col = t>>1, koff = (t&1)*32;
      #pragma unroll
      for (int j=0;j<4;j++){
        unsigned short tmp[8];
        #pragma unroll
        for (int q=0;q<8;q++) tmp[q] = f2bf(Wf[(koff + j*8 + q)*128 + col]);
        *reinterpret_cast<uint4*>(&out[col*128 + half*64 + koff + j*8]) = *reinterpret_cast<const uint4*>(tmp);
      }
    }
    {
      int ce = t>>4;
      int h  = ce & 7;
      if (b < 3){
        const float* av = (ce < 8) ? (as_ + h*16) : (ad_ + h*16);
        float avr[16];
        #pragma unroll
        for (int c2=0;c2<16;c2++) avr[c2] = av[c2];
        #pragma unroll
        for (int i=0;i<4;i++){
          int kl = (t&15) + i*16;
          float s = 0.f;
          #pragma unroll
          for (int c2=0;c2<16;c2++) s += Wf[kl*128 + h*16 + c2]*avr[c2];
          out[(128+ce)*128 + half*64 + kl] = f2bf(s);
        }
      } else {
        #pragma unroll
        for (int i=0;i<4;i++){
          int kl = (t&15) + i*16;
          out[(128+ce)*128 + half*64 + kl] = 0;
        }
      }
    }
    __syncthreads();
  }
}

// =============== MFMA GEMM (no LDS): A[M,128] @ Bt[144,128]bf16; AF32: A is fp32 ===============
template<int AF32>
__global__ __launch_bounds__(256) void k_gemm(
    const void* __restrict__ Ap, const unsigned short* __restrict__ Bt,
    unsigned short* __restrict__ C, float* __restrict__ s_src, float* __restrict__ s_dst, int M)
{
  int t = threadIdx.x, lane = t & 63, w = t >> 6;
  int rA = lane & 15, g = lane >> 4;
  int r0 = blockIdx.x*128 + w*32;
  f32x4 z = {0.f,0.f,0.f,0.f};
  f32x4 acc[2][9];
  #pragma unroll
  for (int mf=0;mf<2;mf++)
    #pragma unroll
    for (int nf=0;nf<9;nf++) acc[mf][nf] = z;

  int rowc0 = min(r0 + rA,      M-1);
  int rowc1 = min(r0 + 16 + rA, M-1);
  #pragma unroll
  for (int ks=0; ks<4; ks++){
    int ko = ks*32 + g*8;
    bf16x8 a0, a1;
    if (AF32){
      const float* Af = (const float*)Ap;
      float4 v0 = ld4(&Af[(size_t)rowc0*128 + ko]);
      float4 v1 = ld4(&Af[(size_t)rowc0*128 + ko + 4]);
      float4 v2 = ld4(&Af[(size_t)rowc1*128 + ko]);
      float4 v3 = ld4(&Af[(size_t)rowc1*128 + ko + 4]);
      a0[0]=(short)f2bf(v0.x); a0[1]=(short)f2bf(v0.y); a0[2]=(short)f2bf(v0.z); a0[3]=(short)f2bf(v0.w);
      a0[4]=(short)f2bf(v1.x); a0[5]=(short)f2bf(v1.y); a0[6]=(short)f2bf(v1.z); a0[7]=(short)f2bf(v1.w);
      a1[0]=(short)f2bf(v2.x); a1[1]=(short)f2bf(v2.y); a1[2]=(short)f2bf(v2.z); a1[3]=(short)f2bf(v2.w);
      a1[4]=(short)f2bf(v3.x); a1[5]=(short)f2bf(v3.y); a1[6]=(short)f2bf(v3.z); a1[7]=(short)f2bf(v3.w);
    } else {
      const unsigned short* A = (const unsigned short*)Ap;
      a0 = *reinterpret_cast<const bf16x8*>(A + (size_t)rowc0*128 + ko);
      a1 = *reinterpret_cast<const bf16x8*>(A + (size_t)rowc1*128 + ko);
    }
    #pragma unroll
    for (int nf=0;nf<9;nf++){
      bf16x8 bf_ = *reinterpret_cast<const bf16x8*>(Bt + (size_t)(nf*16+rA)*128 + ko);
      acc[0][nf] = __builtin_amdgcn_mfma_f32_16x16x32_bf16(a0, bf_, acc[0][nf], 0, 0, 0);
      acc[1][nf] = __builtin_amdgcn_mfma_f32_16x16x32_bf16(a1, bf_, acc[1][nf], 0, 0, 0);
    }
  }

  #pragma unroll
  for (int mf=0;mf<2;mf++){
    #pragma unroll
    for (int r=0;r<4;r++){
      int row = r0 + mf*16 + g*4 + r;
      if (row < M){
        #pragma unroll
        for (int nf=0;nf<8;nf++) C[(size_t)row*128 + nf*16 + rA] = f2bf(acc[mf][nf][r]);
        float sv_ = acc[mf][8][r];
        if (rA < 8) s_src[(size_t)row*8 + rA]     = sv_;
        else        s_dst[(size_t)row*8 + rA - 8] = sv_;
      }
    }
  }
}

// =============== softmax-aggregate: 2 nodes/wave, 16 lanes/row, 2 loads in flight ===============
__global__ __launch_bounds__(256) void k_aggregate(
    const int* __restrict__ off, const int* __restrict__ csr,
    const unsigned short* __restrict__ htmp, const float* __restrict__ s_src,
    const float* __restrict__ s_dst, const float* __restrict__ bias,
    unsigned short* __restrict__ hout, int N_)
{
  __shared__ float esc[4][2][288];   // [wave][half][h*36 + e], e<32; stride 36 => 8 heads on distinct banks
  __shared__ int   ssrc[4][2][32];
  int w = threadIdx.x >> 6;
  int lane = threadIdx.x & 63;
  int half = lane >> 5;      // node select within wave
  int l32  = lane & 31;
  int c2   = l32 & 15;       // 16B chunk of the 256B row (8 channels)
  int eo   = l32 >> 4;       // edge parity 0/1
  int myh  = c2 >> 1;        // head of my channels
  int n = blockIdx.x*8 + w*2 + half;
  int base = 0, deg = 0;
  if (n < N_){ base = off[n]; deg = off[n+1] - base; }
  float sdv[8] = {0.f,0.f,0.f,0.f,0.f,0.f,0.f,0.f};
  if (n < N_){
    float4 sd0 = ld4(&s_dst[(size_t)n*8]);
    float4 sd1 = ld4(&s_dst[(size_t)n*8+4]);
    sdv[0]=sd0.x; sdv[1]=sd0.y; sdv[2]=sd0.z; sdv[3]=sd0.w;
    sdv[4]=sd1.x; sdv[5]=sd1.y; sdv[6]=sd1.z; sdv[7]=sd1.w;
  }
  float acc0=0.f,acc1=0.f,acc2=0.f,acc3=0.f,acc4=0.f,acc5=0.f,acc6=0.f,acc7=0.f;
  float dsum = 0.f;
  const char* hb = (const char*)htmp + (c2<<4);

  for (int cb=0; cb<deg; cb+=32){
    int cdeg = min(32, deg-cb);
    int srcj = 0;
    float ee[8];
    if (l32 < cdeg){
      srcj = csr[base+cb+l32];
      float4 a0 = ld4(&s_src[(size_t)srcj*8]);
      float4 a1 = ld4(&s_src[(size_t)srcj*8+4]);
      float sv[8] = {a0.x,a0.y,a0.z,a0.w,a1.x,a1.y,a1.z,a1.w};
      #pragma unroll
      for (int h=0;h<8;h++){
        float v = sv[h] + sdv[h];
        v = v > 0.f ? v : 0.2f*v;
        ee[h] = __expf(v);
      }
    } else {
      #pragma unroll
      for (int h=0;h<8;h++) ee[h] = 0.f;
    }
    ssrc[w][half][l32] = srcj;
    #pragma unroll
    for (int h=0;h<8;h++) esc[w][half][h*36 + l32] = ee[h];
    asm volatile("s_waitcnt lgkmcnt(0)" ::: "memory");
    __builtin_amdgcn_sched_barrier(0);

    for (int j=0; j<cdeg; j+=4){
      int e0 = j + eo;
      int e1 = j + 2 + eo;
      int s0 = ssrc[w][half][e0];
      int s1 = ssrc[w][half][e1];
      float ev0 = esc[w][half][myh*36 + e0];
      float ev1 = esc[w][half][myh*36 + e1];
      uint4 u0 = *reinterpret_cast<const uint4*>(hb + ((size_t)(unsigned)s0<<8));
      uint4 u1 = *reinterpret_cast<const uint4*>(hb + ((size_t)(unsigned)s1<<8));
      acc0 = fmaf(ev0, bflo(u0.x), acc0);
      acc1 = fmaf(ev0, bfhi(u0.x), acc1);
      acc2 = fmaf(ev0, bflo(u0.y), acc2);
      acc3 = fmaf(ev0, bfhi(u0.y), acc3);
      acc4 = fmaf(ev0, bflo(u0.z), acc4);
      acc5 = fmaf(ev0, bfhi(u0.z), acc5);
      acc6 = fmaf(ev0, bflo(u0.w), acc6);
      acc7 = fmaf(ev0, bfhi(u0.w), acc7);
      acc0 = fmaf(ev1, bflo(u1.x), acc0);
      acc1 = fmaf(ev1, bfhi(u1.x), acc1);
      acc2 = fmaf(ev1, bflo(u1.y), acc2);
      acc3 = fmaf(ev1, bfhi(u1.y), acc3);
      acc4 = fmaf(ev1, bflo(u1.z), acc4);
      acc5 = fmaf(ev1, bfhi(u1.z), acc5);
      acc6 = fmaf(ev1, bflo(u1.w), acc6);
      acc7 = fmaf(ev1, bfhi(u1.w), acc7);
      dsum += ev0 + ev1;
    }
  }
  // merge the 2 edge-parity groups (xor 16 stays within the 32-lane half)
  acc0 += __shfl_xor(acc0, 16);
  acc1 += __shfl_xor(acc1, 16);
  acc2 += __shfl_xor(acc2, 16);
  acc3 += __shfl_xor(acc3, 16);
  acc4 += __shfl_xor(acc4, 16);
  acc5 += __shfl_xor(acc5, 16);
  acc6 += __shfl_xor(acc6, 16);
  acc7 += __shfl_xor(acc7, 16);
  dsum += __shfl_xor(dsum, 16);

  if (n < N_ && eo == 0){
    float inv = 1.f/(dsum + 1e-16f);
    float4 b0 = ld4(&bias[c2*8]);
    float4 b1 = ld4(&bias[c2*8+4]);
    float o0 = fmaf(acc0, inv, b0.x);
    float o1 = fmaf(acc1, inv, b0.y);
    float o2 = fmaf(acc2, inv, b0.z);
    float o3 = fmaf(acc3, inv, b0.w);
    float o4 = fmaf(acc4, inv, b1.x);
    float o5 = fmaf(acc5, inv, b1.y);
    float o6 = fmaf(acc6, inv, b1.z);
    float o7 = fmaf(acc7, inv, b1.w);
    o0 = o0>0.f ? o0 : (__expf(o0)-1.f);
    o1 = o1>0.f ? o1 : (__expf(o1)-1.f);
    o2 = o2>0.f ? o2 : (__expf(o2)-1.f);
    o3 = o3>0.f ? o3 : (__expf(o3)-1.f);
    o4 = o4>0.f ? o4 : (__expf(o4)-1.f);
    o5 = o5>0.f ? o5 : (__expf(o5)-1.f);
    o6 = o6>0.f ? o6 : (__expf(o6)-1.f);
    o7 = o7>0.f ? o7 : (__expf(o7)-1.f);
    uint4 pk;
    pk.x = (unsigned)f2bf(o0) | ((unsigned)f2bf(o1)<<16);
    pk.y = (unsigned)f2bf(o2) | ((unsigned)f2bf(o3)<<16);
    pk.z = (unsigned)f2bf(o4) | ((unsigned)f2bf(o5)<<16);
    pk.w = (unsigned)f2bf(o6) | ((unsigned)f2bf(o7)<<16);
    *reinterpret_cast<uint4*>(&hout[(size_t)n*128 + c2*8]) = pk;
  }
}

// =============== fused final v4: A-frag preload + B-share across layers ===============
// NOTE: no min-waves clamp ((256,4) caused 64-VGPR cap -> 134 MB spill, rounds 5/6).
__global__ __launch_bounds__(256) void k_final4(
    const unsigned short* __restrict__ h0, const unsigned short* __restrict__ h1,
    const unsigned short* __restrict__ h2,
    const unsigned short* __restrict__ WattT, const float* __restrict__ aatt,
    const unsigned short* __restrict__ WoutT,  // [48][128] hi, then [48][128] lo
    const float* __restrict__ bout, float* __restrict__ out, int M)
{
  int t = threadIdx.x, lane = t & 63, w = t >> 6;
  int rA = lane & 15, g = lane >> 4;
  int r0 = blockIdx.x*64 + w*16;
  int rowc = min(r0 + rA, M-1);

  float av[8];
  #pragma unroll
  for (int nf=0;nf<8;nf++) av[nf] = aatt[nf*16 + rA];

  bf16x8 a[3][4];
  #pragma unroll
  for (int ks=0;ks<4;ks++){
    int ko = ks*32 + g*8;
    a[0][ks] = *reinterpret_cast<const bf16x8*>(h0 + (size_t)rowc*128 + ko);
    a[1][ks] = *reinterpret_cast<const bf16x8*>(h1 + (size_t)rowc*128 + ko);
    a[2][ks] = *reinterpret_cast<const bf16x8*>(h2 + (size_t)rowc*128 + ko);
  }

  float sc[3][4];
  #pragma unroll
  for (int l=0;l<3;l++)
    #pragma unroll
    for (int r=0;r<4;r++) sc[l][r] = 0.f;

  #pragma unroll
  for (int ch=0; ch<4; ch++){
    f32x4 acc[3][2];
    #pragma unroll
    for (int l=0;l<3;l++){ acc[l][0] = (f32x4){0.f,0.f,0.f,0.f}; acc[l][1] = (f32x4){0.f,0.f,0.f,0.f}; }
    #pragma unroll
    for (int ks=0; ks<4; ks++){
      int ko = ks*32 + g*8;
      bf16x8 b0 = *reinterpret_cast<const bf16x8*>(WattT + (size_t)((ch*2+0)*16+rA)*128 + ko);
      bf16x8 b1 = *reinterpret_cast<const bf16x8*>(WattT + (size_t)((ch*2+1)*16+rA)*128 + ko);
      #pragma unroll
      for (int l=0;l<3;l++){
        acc[l][0] = __builtin_amdgcn_mfma_f32_16x16x32_bf16(a[l][ks], b0, acc[l][0], 0, 0, 0);
        acc[l][1] = __builtin_amdgcn_mfma_f32_16x16x32_bf16(a[l][ks], b1, acc[l][1], 0, 0, 0);
      }
    }
    float w0 = av[ch*2], w1 = av[ch*2+1];
    #pragma unroll
    for (int l=0;l<3;l++)
      #pragma unroll
      for (int r=0;r<4;r++)
        sc[l][r] += ftanh(acc[l][0][r])*w0 + ftanh(acc[l][1][r])*w1;
  }
  #pragma unroll
  for (int l=0;l<3;l++)
    #pragma unroll
    for (int r=0;r<4;r++){
      float s = sc[l][r];
      s += __shfl_xor(s, 1);
      s += __shfl_xor(s, 2);
      s += __shfl_xor(s, 4);
      s += __shfl_xor(s, 8);
      sc[l][r] = s;
    }

  float lam[3][4];
  #pragma unroll
  for (int r=0;r<4;r++){
    float m = fmaxf(sc[0][r], fmaxf(sc[1][r], sc[2][r]));
    float e0 = __expf(sc[0][r]-m), e1 = __expf(sc[1][r]-m), e2 = __expf(sc[2][r]-m);
    float inv = 1.f/(e0+e1+e2);
    lam[0][r]=e0*inv; lam[1][r]=e1*inv; lam[2][r]=e2*inv;
  }
  int rsel = rA & 3;
  int srcLane = ((rA>>2)<<4) | rA;
  float p0 = rsel==0 ? lam[0][0] : rsel==1 ? lam[0][1] : rsel==2 ? lam[0][2] : lam[0][3];
  float p1 = rsel==0 ? lam[1][0] : rsel==1 ? lam[1][1] : rsel==2 ? lam[1][2] : lam[1][3];
  float p2 = rsel==0 ? lam[2][0] : rsel==1 ? lam[2][1] : rsel==2 ? lam[2][2] : lam[2][3];
  float lamA[3];
  lamA[0] = __shfl(p0, srcLane);
  lamA[1] = __shfl(p1, srcLane);
  lamA[2] = __shfl(p2, srcLane);

  f32x4 oacc[3];
  #pragma unroll
  for (int nf=0;nf<3;nf++) oacc[nf] = (f32x4){0.f,0.f,0.f,0.f};
  #pragma unroll
  for (int ks=0;ks<4;ks++){
    int ko = ks*32 + g*8;
    bf16x8 asc[3];
    #pragma unroll
    for (int l=0;l<3;l++){
      #pragma unroll
      for (int i=0;i<8;i++) asc[l][i] = (short)f2bf(bfs(a[l][ks][i]) * lamA[l]);
    }
    #pragma unroll
    for (int nf=0;nf<3;nf++){
      bf16x8 bh = *reinterpret_cast<const bf16x8*>(WoutT + (size_t)(nf*16+rA)*128 + ko);
      bf16x8 bl = *reinterpret_cast<const bf16x8*>(WoutT + 6144 + (size_t)(nf*16+rA)*128 + ko);
      #pragma unroll
      for (int l=0;l<3;l++){
        oacc[nf] = __builtin_amdgcn_mfma_f32_16x16x32_bf16(asc[l], bh, oacc[nf], 0, 0, 0);
        oacc[nf] = __builtin_amdgcn_mfma_f32_16x16x32_bf16(asc[l], bl, oacc[nf], 0, 0, 0);
      }
    }
  }

  #pragma unroll
  for (int nf=0;nf<3;nf++){
    int col = nf*16 + rA;
    float bv = (col < 40) ? bout[col] : 0.f;
    #pragma unroll
    for (int r=0;r<4;r++){
      int row = r0 + g*4 + r;
      if (row < M && col < 40) out[(size_t)row*40 + col] = oacc[nf][r] + bv;
    }
  }
}

extern "C" void kernel_launch(void* const* d_in, const int* in_sizes, int n_in,
                              void* d_out, int out_size, void* d_ws, size_t ws_size,
                              hipStream_t stream)
{
  const float* x    = (const float*)d_in[0];
  const int*   ei   = (const int*)d_in[1];
  const float* W0   = (const float*)d_in[2];
  const float* as0  = (const float*)d_in[3];
  const float* ad0  = (const float*)d_in[4];
  const float* b0   = (const float*)d_in[5];
  const float* W12  = (const float*)d_in[6];
  const float* as12 = (const float*)d_in[7];
  const float* ad12 = (const float*)d_in[8];
  const float* b12  = (const float*)d_in[9];
  const float* Watt = (const float*)d_in[10];
  const float* aatt = (const float*)d_in[11];
  const float* Wout = (const float*)d_in[12];
  const float* bout = (const float*)d_in[13];
  const int N_ = in_sizes[0] / 128;
  const int E_ = in_sizes[1] / 2;
  const int Et = E_ + N_;
  const int nb = (N_ + 1023) >> 10;

  char* p = (char*)d_ws;
  auto carve = [&](size_t bytes)->char*{ char* r = p; p += (bytes + 255) & ~(size_t)255; return r; };
  unsigned short* htmp = (unsigned short*)carve((size_t)N_*128*2);
  unsigned short* h0   = (unsigned short*)carve((size_t)N_*128*2);
  unsigned short* h1   = (unsigned short*)carve((size_t)N_*128*2);
  unsigned short* h2   = (unsigned short*)carve((size_t)N_*128*2);
  unsigned short* wsT  = (unsigned short*)carve((size_t)(5*18432 + 48*128)*2);
  float* ssrc_s  = (float*)carve((size_t)N_*8*4);
  float* sdst_s  = (float*)carve((size_t)N_*8*4);
  int* offv      = (int*)carve((size_t)(N_+1)*4);
  int* bcnt      = (int*)carve((size_t)64*4);
  int* bbase     = (int*)carve((size_t)64*4);
  unsigned* bdata= (unsigned*)carve((size_t)64*BCAP*4);
  int* csr       = (int*)carve((size_t)Et*4);

  k_prep<<<5,256,0,stream>>>(W0, W12, Watt, as0, ad0, as12, ad12, Wout, wsT);

  hipMemsetAsync(bcnt, 0, 64*4, stream);
  int gB = (Et + 2047)/2048;
  k_bucket<<<gB,256,0,stream>>>(ei, bcnt, bdata, E_, Et);
  k_binit<<<1,64,0,stream>>>(bcnt, bbase, offv, N_, nb);
  k_bfinish<<<nb,512,0,stream>>>(bdata, bcnt, bbase, offv, csr, N_);

  int gM  = (N_+127)/128;
  int gN8 = (N_+7)/8;
  int gF  = (N_+63)/64;
  unsigned short* hl[3] = {h0,h1,h2};
  for (int l=0;l<3;l++){
    const float* bb = (l==0)? b0 : b12 + (size_t)(l-1)*128;
    const unsigned short* Bt = wsT + (size_t)l*18432;
    if (l==0)
      k_gemm<1><<<gM,256,0,stream>>>((const void*)x, Bt, htmp, ssrc_s, sdst_s, N_);
    else
      k_gemm<0><<<gM,256,0,stream>>>((const void*)hl[l-1], Bt, htmp, ssrc_s, sdst_s, N_);
    k_aggregate<<<gN8,256,0,stream>>>(offv, csr, htmp, ssrc_s, sdst_s, bb, hl[l], N_);
  }
  k_final4<<<gF,256,0,stream>>>(h0, h1, h2, wsT + (size_t)3*18432, aatt,
                                wsT + (size_t)4*18432, bout, (float*)d_out, N_);
}